// Round 5
// baseline (6075.151 us; speedup 1.0000x reference)
//
#include <hip/hip_runtime.h>

// R5: tag-publish sync (no contended RMW). R4's 7.4us/step was barrier
// protocol latency (32 serialized fetch_adds + 2-hop publish + LDS staging).
// Now: producer stores s-tile (coherent 2B stores) -> vmcnt(0) -> tag=t+1
// into packed 32-dword team line; consumers ballot-poll the line (lane i
// polls tag i), then load MFMA fragments DIRECTLY from publish slots.
// Decomposition unchanged: per LSTM, 4 batch-teams x 32 hidden-blocks;
// folded recurrence gates = b + x.Wih^T + s.Wc^T, Wc = Whh@Whr prologue;
// blkh<16 blocks also compute out(t-1) = s(t-1).Whr^T (Whr in regs).
constexpr int kB = 64, kT = 512, kD = 256, kH = 512, kG = 2048;
constexpr int kNB = 256, kNT = 256;

typedef __attribute__((ext_vector_type(8))) short bf16x8;
typedef __attribute__((ext_vector_type(4))) float f32x4;
union U4 { unsigned u[4]; bf16x8 v; };

__device__ __forceinline__ ushort f2bf(float x) {
    union { float f; unsigned u; } v; v.f = x;
    unsigned r = v.u + 0x7FFFu + ((v.u >> 16) & 1u);
    return (ushort)(r >> 16);
}
__device__ __forceinline__ unsigned pk2(float a, float b) {
    return (unsigned)f2bf(a) | ((unsigned)f2bf(b) << 16);
}
__device__ __forceinline__ float sigm(float x) { return 1.f / (1.f + __expf(-x)); }

#define AT_LOAD(p)     __hip_atomic_load((p), __ATOMIC_RELAXED, __HIP_MEMORY_SCOPE_AGENT)
#define AT_STORE(p,v)  __hip_atomic_store((p), (v), __ATOMIC_RELAXED, __HIP_MEMORY_SCOPE_AGENT)
#define AT_ADD(p,v)    __hip_atomic_fetch_add((p), (v), __ATOMIC_RELAXED, __HIP_MEMORY_SCOPE_AGENT)
#define VMCNT0() asm volatile("s_waitcnt vmcnt(0)" ::: "memory")

// ws dword layout:
//   [0]        global one-time ctr     [64] global one-time flag
//   [256,768)  tags: line per (l,bt,par) = ((l*4+bt)*2+par)*32 + producer
//   [1024,66560)  sdata: slot ((l*4+bt)*2+par)*32+p, 128 dwords (16x16 bf16)
//   [66560, +2*2048*256)  Wc bf16 (dword-packed pairs)
__global__ void bar_init_kernel(unsigned* ws) {
    int i = blockIdx.x * 1024 + threadIdx.x;
    if (i < 66560) AT_STORE(ws + i, 0u);
}

__global__ void __launch_bounds__(kNT, 1) lstm2_kernel(
    const float* __restrict__ x1, const float* __restrict__ x2,
    const float* __restrict__ wih1, const float* __restrict__ whh1,
    const float* __restrict__ b1,   const float* __restrict__ whr1,
    const float* __restrict__ wih2, const float* __restrict__ whh2,
    const float* __restrict__ b2,   const float* __restrict__ whr2,
    float* __restrict__ out, unsigned* __restrict__ ws)
{
    const int bid = blockIdx.x, tid = threadIdx.x;
    const int l = bid >> 7, b7 = bid & 127;
    const int bteam = b7 >> 5, blkh = b7 & 31;
    const int h0 = blkh * 16, grow0 = bteam * 16;
    const int l4bt = l * 4 + bteam;

    const float* x   = l ? x2 : x1;
    const float* wih = l ? wih2 : wih1;
    const float* whh = l ? whh2 : whh1;
    const float* bb  = l ? b2 : b1;
    const float* whr = l ? whr2 : whr1;
    float* outp = out + (l ? (size_t)0 : (size_t)kB * kT * kD);

    unsigned* TG = ws + 256;
    unsigned* SD = ws + 1024;
    unsigned* WC = ws + 66560;

    __shared__ float lgs[4][16][17];

    // ---------- P0: Wc = Whh @ Whr (f32 accum -> bf16, coherent stores) -----
    {
        const int j  = b7 * 16 + (tid >> 4);               // gate col 0..2047
        const int k0 = (tid & 15) * 32;
        const float* whh_r = whh + (size_t)j * kD;
        float acc[32];
        #pragma unroll
        for (int i = 0; i < 32; i++) acc[i] = 0.f;
        for (int p = 0; p < kD; p++) {
            float w = whh_r[p];
            const float4* wr = (const float4*)(whr + (size_t)p * kH + k0);
            #pragma unroll
            for (int q = 0; q < 8; q++) {
                float4 v = wr[q];
                acc[q*4+0] = fmaf(w, v.x, acc[q*4+0]);
                acc[q*4+1] = fmaf(w, v.y, acc[q*4+1]);
                acc[q*4+2] = fmaf(w, v.z, acc[q*4+2]);
                acc[q*4+3] = fmaf(w, v.w, acc[q*4+3]);
            }
        }
        unsigned* dst = WC + (size_t)l * kG * 256 + (size_t)j * 256 + k0 / 2;
        #pragma unroll
        for (int i = 0; i < 16; i++) AT_STORE(dst + i, pk2(acc[2*i], acc[2*i+1]));
    }
    VMCNT0();
    __syncthreads();
    if (tid == 0) {                                        // one-time barrier
        unsigned a = AT_ADD(ws + 0, 1u);
        if (a == (unsigned)(kNB - 1)) AT_STORE(ws + 64, 1u);
        while (AT_LOAD(ws + 64) == 0u) __builtin_amdgcn_s_sleep(2);
    }
    __syncthreads();

    // ---------- persistent fragments -----------------------------------------
    const int wv = tid >> 6, lane = tid & 63;
    const int n = lane & 15, kq = lane >> 4;
    const int gcol = wv * kH + h0 + n;                     // wave wv = gate wv
    const float bias = bb[gcol];
    const int mrow = grow0 + n;
    const int crow = tid >> 4, ccol = tid & 15;

    bf16x8 bxh[8];                                         // Wih frags (K=256)
    #pragma unroll
    for (int ks = 0; ks < 8; ks++) {
        const float4* p = (const float4*)(wih + (size_t)gcol * kD + ks * 32 + kq * 8);
        float4 a0 = p[0], a1 = p[1];
        U4 h;
        h.u[0] = pk2(a0.x, a0.y); h.u[1] = pk2(a0.z, a0.w);
        h.u[2] = pk2(a1.x, a1.y); h.u[3] = pk2(a1.z, a1.w);
        bxh[ks] = h.v;
    }
    bf16x8 bsh[16];                                        // Wc frags (K=512)
    {
        const unsigned* wcp = WC + (size_t)l * kG * 256 + (size_t)gcol * 256;
        #pragma unroll
        for (int ks = 0; ks < 16; ks++) {
            U4 u;
            #pragma unroll
            for (int i = 0; i < 4; i++) u.u[i] = AT_LOAD(wcp + ks * 16 + kq * 4 + i);
            bsh[ks] = u.v;
        }
    }
    const bool isProj = (blkh < 16);
    bf16x8 bp[16];                                         // Whr frags (proj blks)
    if (isProj) {
        const int pcol = blkh * 16 + n;
        #pragma unroll
        for (int ks = 0; ks < 16; ks++) {
            const float4* p = (const float4*)(whr + (size_t)pcol * kH + ks * 32 + kq * 8);
            float4 a0 = p[0], a1 = p[1];
            U4 h;
            h.u[0] = pk2(a0.x, a0.y); h.u[1] = pk2(a0.z, a0.w);
            h.u[2] = pk2(a1.x, a1.y); h.u[3] = pk2(a1.z, a1.w);
            bp[ks] = h.v;
        }
    }

    bf16x8 ax[8];                                          // x(t) frags
    #pragma unroll
    for (int ks = 0; ks < 8; ks++) {
        const float4* xp = (const float4*)(x + (size_t)mrow * kT * kD + ks * 32 + kq * 8);
        float4 a0 = xp[0], a1 = xp[1];
        U4 f;
        f.u[0] = pk2(a0.x, a0.y); f.u[1] = pk2(a0.z, a0.w);
        f.u[2] = pk2(a1.x, a1.y); f.u[3] = pk2(a1.z, a1.w);
        ax[ks] = f.v;
    }
    float creg = 0.f;
    const int dof = n * 8 + 4 * (kq & 1);                  // frag dword offset in tile

    // ---------- main loop: tag-publish sync, one poll per step ---------------
    for (int t = 0; t <= kT; ++t) {
        if (t == kT && !isProj) break;
        const int par = (t + 1) & 1;
        const unsigned want = (unsigned)t;
        const unsigned* tagp = TG + (l4bt * 2 + par) * 32;
        while (true) {                                     // ballot poll, all waves
            unsigned tg = (lane < 32) ? AT_LOAD(tagp + lane) : want;
            if (__all((int)(tg >= want))) break;
            __builtin_amdgcn_s_sleep(1);
        }
        __builtin_amdgcn_sched_barrier(0);

        const unsigned* sp = SD + (size_t)(l4bt * 2 + par) * 32 * 128;
        bf16x8 as[16];                                     // s(t-1) frags, direct
        #pragma unroll
        for (int ks = 0; ks < 16; ks++) {
            const unsigned* tp = sp + (2 * ks + (kq >> 1)) * 128 + dof;
            U4 u;
            u.u[0] = AT_LOAD(tp + 0); u.u[1] = AT_LOAD(tp + 1);
            u.u[2] = AT_LOAD(tp + 2); u.u[3] = AT_LOAD(tp + 3);
            as[ks] = u.v;
        }

        if (t < kT) {
            f32x4 c0 = {bias, bias, bias, bias};
            f32x4 c1 = {0.f, 0.f, 0.f, 0.f};
            f32x4 c2 = {0.f, 0.f, 0.f, 0.f};
            #pragma unroll
            for (int ks = 0; ks < 8; ks++) {
                c0 = __builtin_amdgcn_mfma_f32_16x16x32_bf16(ax[ks],    bxh[ks],   c0, 0, 0, 0);
                c1 = __builtin_amdgcn_mfma_f32_16x16x32_bf16(as[ks],    bsh[ks],   c1, 0, 0, 0);
                c2 = __builtin_amdgcn_mfma_f32_16x16x32_bf16(as[8+ks],  bsh[8+ks], c2, 0, 0, 0);
            }
            #pragma unroll
            for (int r = 0; r < 4; r++)
                lgs[wv][kq * 4 + r][n] = c0[r] + c1[r] + c2[r];
            __syncthreads();
            const float gi = sigm(lgs[0][crow][ccol]);
            const float gf = sigm(lgs[1][crow][ccol]);
            const float gg = tanhf(lgs[2][crow][ccol]);
            const float go = sigm(lgs[3][crow][ccol]);
            creg = gf * creg + gi * gg;
            const float sv = go * tanhf(creg);
            // publish own 2B element of the s(t) tile, then tag
            ushort* sown = (ushort*)(SD + (size_t)((l4bt * 2 + (t & 1)) * 32 + blkh) * 128);
            __hip_atomic_store(sown + crow * 16 + ccol, f2bf(sv),
                               __ATOMIC_RELAXED, __HIP_MEMORY_SCOPE_AGENT);
            VMCNT0();
            __syncthreads();
            if (tid == 0)
                AT_STORE(TG + (l4bt * 2 + (t & 1)) * 32 + blkh, (unsigned)(t + 1));
        }

        if (t >= 1 && isProj) {                            // out(t-1) = s(t-1).Whr^T
            f32x4 p0 = {0.f, 0.f, 0.f, 0.f};
            f32x4 p1 = {0.f, 0.f, 0.f, 0.f};
            #pragma unroll
            for (int ks = 0; ks < 8; ks++) {
                p0 = __builtin_amdgcn_mfma_f32_16x16x32_bf16(as[ks],     bp[ks],     p0, 0, 0, 0);
                p1 = __builtin_amdgcn_mfma_f32_16x16x32_bf16(as[8 + ks], bp[8 + ks], p1, 0, 0, 0);
            }
            const int pcol = blkh * 16 + n;
            #pragma unroll
            for (int r = 0; r < 4; r++)
                outp[((size_t)(grow0 + kq * 4 + r) * kT + (t - 1)) * kD + pcol] = p0[r] + p1[r];
        }

        if (t + 1 < kT) {                                  // prefetch x(t+1)
            #pragma unroll
            for (int ks = 0; ks < 8; ks++) {
                const float4* xp = (const float4*)(x + ((size_t)mrow * kT + (t + 1)) * kD + ks * 32 + kq * 8);
                float4 a0 = xp[0], a1 = xp[1];
                U4 f;
                f.u[0] = pk2(a0.x, a0.y); f.u[1] = pk2(a0.z, a0.w);
                f.u[2] = pk2(a1.x, a1.y); f.u[3] = pk2(a1.z, a1.w);
                ax[ks] = f.v;
            }
        }
    }
}

extern "C" void kernel_launch(void* const* d_in, const int* in_sizes, int n_in,
                              void* d_out, int out_size, void* d_ws, size_t ws_size,
                              hipStream_t stream) {
    const float* x1   = (const float*)d_in[0];
    const float* x2   = (const float*)d_in[1];
    const float* wih1 = (const float*)d_in[2];
    const float* whh1 = (const float*)d_in[3];
    const float* b1   = (const float*)d_in[4];
    const float* whr1 = (const float*)d_in[5];
    const float* wih2 = (const float*)d_in[6];
    const float* whh2 = (const float*)d_in[7];
    const float* b2   = (const float*)d_in[8];
    const float* whr2 = (const float*)d_in[9];
    float* outp  = (float*)d_out;
    unsigned* ws = (unsigned*)d_ws;

    bar_init_kernel<<<65, 1024, 0, stream>>>(ws);
    lstm2_kernel<<<dim3(kNB), dim3(kNT), 0, stream>>>(
        x1, x2, wih1, whh1, b1, whr1, wih2, whh2, b2, whr2, outp, ws);
}

// Round 6
// 3066.743 us; speedup vs baseline: 1.9810x; 1.9810x over previous
//
#include <hip/hip_runtime.h>

// R6: tag-line sync (R5, no contended RMW) + LDS-shared staging (R4) with
// wide 8B coherent loads. R5's regression = 4x redundant scalar uncached
// frag loads (16MB/step chip-wide at 4B granule => ~8us/step L3 service).
// Now each block stages the 16KB s-slab ONCE (8 x ull loads/thread,
// coalesced row-major), shares via LDS. Publish is row-major 2B stores.
// Geometry: per LSTM, 4 batch-teams x 32 hidden-blocks (16 cols each);
// folded recurrence gates = b + x.Wih^T + s.Wc^T (Wc = Whh@Whr prologue);
// blkh<16 blocks also do out(t-1) = s(t-1).Whr^T in the sync shadow.
constexpr int kB = 64, kT = 512, kD = 256, kH = 512, kG = 2048;
constexpr int kNB = 256, kNT = 256;

typedef __attribute__((ext_vector_type(8))) short bf16x8;
typedef __attribute__((ext_vector_type(4))) float f32x4;
typedef unsigned long long ull;
union U4 { unsigned u[4]; ull q[2]; bf16x8 v; };

__device__ __forceinline__ ushort f2bf(float x) {
    union { float f; unsigned u; } v; v.f = x;
    unsigned r = v.u + 0x7FFFu + ((v.u >> 16) & 1u);
    return (ushort)(r >> 16);
}
__device__ __forceinline__ unsigned pk2(float a, float b) {
    return (unsigned)f2bf(a) | ((unsigned)f2bf(b) << 16);
}
__device__ __forceinline__ float sigm(float x) { return 1.f / (1.f + __expf(-x)); }

#define AT_LOAD(p)     __hip_atomic_load((p), __ATOMIC_RELAXED, __HIP_MEMORY_SCOPE_AGENT)
#define AT_LOAD64(p)   __hip_atomic_load((p), __ATOMIC_RELAXED, __HIP_MEMORY_SCOPE_AGENT)
#define AT_STORE(p,v)  __hip_atomic_store((p), (v), __ATOMIC_RELAXED, __HIP_MEMORY_SCOPE_AGENT)
#define AT_ADD(p,v)    __hip_atomic_fetch_add((p), (v), __ATOMIC_RELAXED, __HIP_MEMORY_SCOPE_AGENT)
#define VMCNT0() asm volatile("s_waitcnt vmcnt(0)" ::: "memory")

// ws dword layout:
//  [0] one-time ctr   [64] one-time flag
//  [256,768)    tags: line of 32 per (l,bt,par): ((l*4+bt)*2+par)*32 + blkh
//  [1024,66560) SD: slot ((l*4+bt)*2+par) * 4096 dw, row-major [16][512] bf16
//  [66560,+2*2048*256) WC: Wc bf16, [l][2048 gate rows][512 k]
__global__ void bar_init_kernel(unsigned* ws) {
    int i = blockIdx.x * 1024 + threadIdx.x;
    if (i < 66560) AT_STORE(ws + i, 0u);
}

__global__ void __launch_bounds__(kNT, 1) lstm2_kernel(
    const float* __restrict__ x1, const float* __restrict__ x2,
    const float* __restrict__ wih1, const float* __restrict__ whh1,
    const float* __restrict__ b1,   const float* __restrict__ whr1,
    const float* __restrict__ wih2, const float* __restrict__ whh2,
    const float* __restrict__ b2,   const float* __restrict__ whr2,
    float* __restrict__ out, unsigned* __restrict__ ws)
{
    const int bid = blockIdx.x, tid = threadIdx.x;
    const int l = bid >> 7, b7 = bid & 127;
    const int bteam = b7 >> 5, blkh = b7 & 31;
    const int h0 = blkh * 16, grow0 = bteam * 16;
    const int l4bt = l * 4 + bteam;

    const float* x   = l ? x2 : x1;
    const float* wih = l ? wih2 : wih1;
    const float* whh = l ? whh2 : whh1;
    const float* bb  = l ? b2 : b1;
    const float* whr = l ? whr2 : whr1;
    float* outp = out + (l ? (size_t)0 : (size_t)kB * kT * kD);

    unsigned* TG  = ws + 256;
    unsigned* SDB = ws + 1024;
    unsigned* WC  = ws + 66560;

    __shared__ unsigned sst[16 * 268];                 // staged s(t-1), row pad 268
    __shared__ float lgs[4][16][17];

    // ---------- P0: Wc = Whh @ Whr (f32 accum -> bf16, coherent stores) -----
    {
        const int j  = b7 * 16 + (tid >> 4);           // gate row 0..2047
        const int k0 = (tid & 15) * 32;
        const float* whh_r = whh + (size_t)j * kD;
        float acc[32];
        #pragma unroll
        for (int i = 0; i < 32; i++) acc[i] = 0.f;
        for (int p = 0; p < kD; p++) {
            float w = whh_r[p];
            const float4* wr = (const float4*)(whr + (size_t)p * kH + k0);
            #pragma unroll
            for (int q = 0; q < 8; q++) {
                float4 v = wr[q];
                acc[q*4+0] = fmaf(w, v.x, acc[q*4+0]);
                acc[q*4+1] = fmaf(w, v.y, acc[q*4+1]);
                acc[q*4+2] = fmaf(w, v.z, acc[q*4+2]);
                acc[q*4+3] = fmaf(w, v.w, acc[q*4+3]);
            }
        }
        unsigned* dst = WC + (size_t)l * kG * 256 + (size_t)j * 256 + k0 / 2;
        #pragma unroll
        for (int i = 0; i < 16; i++) AT_STORE(dst + i, pk2(acc[2*i], acc[2*i+1]));
    }
    VMCNT0();
    __syncthreads();
    if (tid == 0) {                                    // one-time barrier
        unsigned a = AT_ADD(ws + 0, 1u);
        if (a == (unsigned)(kNB - 1)) AT_STORE(ws + 64, 1u);
        while (AT_LOAD(ws + 64) == 0u) __builtin_amdgcn_s_sleep(2);
    }
    __syncthreads();

    // ---------- persistent fragments -----------------------------------------
    const int wv = tid >> 6, lane = tid & 63;
    const int n = lane & 15, kq = lane >> 4;
    const int gcol = wv * kH + h0 + n;                 // wave wv = gate wv
    const float bias = bb[gcol];
    const int mrow = grow0 + n;
    const int crow = tid >> 4, ccol = tid & 15;

    bf16x8 bxh[8];                                     // Wih frags (K=256), plain
    #pragma unroll
    for (int ks = 0; ks < 8; ks++) {
        const float4* p = (const float4*)(wih + (size_t)gcol * kD + ks * 32 + kq * 8);
        float4 a0 = p[0], a1 = p[1];
        U4 h;
        h.u[0] = pk2(a0.x, a0.y); h.u[1] = pk2(a0.z, a0.w);
        h.u[2] = pk2(a1.x, a1.y); h.u[3] = pk2(a1.z, a1.w);
        bxh[ks] = h.v;
    }
    bf16x8 bsh[16];                                    // Wc frags (K=512), coherent
    {
        const ull* wcp = (const ull*)(WC + (size_t)l * kG * 256 + (size_t)gcol * 256);
        #pragma unroll
        for (int ks = 0; ks < 16; ks++) {
            U4 u;
            u.q[0] = AT_LOAD64(wcp + ks * 8 + kq * 2 + 0);
            u.q[1] = AT_LOAD64(wcp + ks * 8 + kq * 2 + 1);
            bsh[ks] = u.v;
        }
    }
    const bool isProj = (blkh < 16);
    bf16x8 bp[16];                                     // Whr frags (proj blocks)
    if (isProj) {
        const int pcol = blkh * 16 + n;
        #pragma unroll
        for (int ks = 0; ks < 16; ks++) {
            const float4* p = (const float4*)(whr + (size_t)pcol * kH + ks * 32 + kq * 8);
            float4 a0 = p[0], a1 = p[1];
            U4 h;
            h.u[0] = pk2(a0.x, a0.y); h.u[1] = pk2(a0.z, a0.w);
            h.u[2] = pk2(a1.x, a1.y); h.u[3] = pk2(a1.z, a1.w);
            bp[ks] = h.v;
        }
    }

    bf16x8 ax[8];                                      // x(t) frags, plain cached
    #pragma unroll
    for (int ks = 0; ks < 8; ks++) {
        const float4* xp = (const float4*)(x + (size_t)mrow * kT * kD + ks * 32 + kq * 8);
        float4 a0 = xp[0], a1 = xp[1];
        U4 f;
        f.u[0] = pk2(a0.x, a0.y); f.u[1] = pk2(a0.z, a0.w);
        f.u[2] = pk2(a1.x, a1.y); f.u[3] = pk2(a1.z, a1.w);
        ax[ks] = f.v;
    }
    float creg = 0.f;

    const int srow = tid >> 4, scol = (tid & 15) * 16; // staging: row, dword col

    // ---------- main loop: tag poll -> LDS stage -> MFMA -> cell -> publish --
    for (int t = 0; t <= kT; ++t) {
        if (t == kT && !isProj) break;
        const int par = (t + 1) & 1;
        const unsigned want = (unsigned)t;
        const unsigned* tagp = TG + (l4bt * 2 + par) * 32;
        while (true) {                                 // ballot poll, all waves
            unsigned tg = (lane < 32) ? AT_LOAD(tagp + lane) : want;
            if (__all((int)(tg >= want))) break;
            __builtin_amdgcn_s_sleep(1);
        }
        __builtin_amdgcn_sched_barrier(0);

        {   // stage s(t-1) slab once per block: 8 x ull coherent loads/thread
            const ull* sp = (const ull*)(SDB + (size_t)(l4bt * 2 + par) * 4096
                                             + srow * 256 + scol);
            ull* ld = (ull*)&sst[srow * 268 + scol];
            ull q0 = AT_LOAD64(sp + 0), q1 = AT_LOAD64(sp + 1);
            ull q2 = AT_LOAD64(sp + 2), q3 = AT_LOAD64(sp + 3);
            ull q4 = AT_LOAD64(sp + 4), q5 = AT_LOAD64(sp + 5);
            ull q6 = AT_LOAD64(sp + 6), q7 = AT_LOAD64(sp + 7);
            ld[0] = q0; ld[1] = q1; ld[2] = q2; ld[3] = q3;
            ld[4] = q4; ld[5] = q5; ld[6] = q6; ld[7] = q7;
        }
        __syncthreads();
        bf16x8 as[16];                                 // A frags from LDS
        #pragma unroll
        for (int ks = 0; ks < 16; ks++)
            as[ks] = *(const bf16x8*)&sst[n * 268 + ks * 16 + kq * 4];

        if (t < kT) {
            f32x4 c0 = {bias, bias, bias, bias};
            f32x4 c1 = {0.f, 0.f, 0.f, 0.f};
            f32x4 c2 = {0.f, 0.f, 0.f, 0.f};
            #pragma unroll
            for (int ks = 0; ks < 8; ks++) {
                c0 = __builtin_amdgcn_mfma_f32_16x16x32_bf16(ax[ks],   bxh[ks],   c0, 0, 0, 0);
                c1 = __builtin_amdgcn_mfma_f32_16x16x32_bf16(as[ks],   bsh[ks],   c1, 0, 0, 0);
                c2 = __builtin_amdgcn_mfma_f32_16x16x32_bf16(as[8+ks], bsh[8+ks], c2, 0, 0, 0);
            }
            #pragma unroll
            for (int r = 0; r < 4; r++)
                lgs[wv][kq * 4 + r][n] = c0[r] + c1[r] + c2[r];
            __syncthreads();
            const float gi = sigm(lgs[0][crow][ccol]);
            const float gf = sigm(lgs[1][crow][ccol]);
            const float gg = tanhf(lgs[2][crow][ccol]);
            const float go = sigm(lgs[3][crow][ccol]);
            creg = gf * creg + gi * gg;
            const float sv = go * tanhf(creg);
            // publish own element row-major, then tag after all stores drain
            ushort* sd = (ushort*)(SDB + (size_t)(l4bt * 2 + (t & 1)) * 4096);
            __hip_atomic_store(sd + crow * 512 + h0 + ccol, f2bf(sv),
                               __ATOMIC_RELAXED, __HIP_MEMORY_SCOPE_AGENT);
            VMCNT0();
            __syncthreads();
            if (tid == 0)
                AT_STORE(TG + (l4bt * 2 + (t & 1)) * 32 + blkh, (unsigned)(t + 1));
        }

        if (t >= 1 && isProj) {                        // out(t-1), sync shadow
            f32x4 p0 = {0.f, 0.f, 0.f, 0.f};
            f32x4 p1 = {0.f, 0.f, 0.f, 0.f};
            #pragma unroll
            for (int ks = 0; ks < 8; ks++) {
                p0 = __builtin_amdgcn_mfma_f32_16x16x32_bf16(as[ks],     bp[ks],     p0, 0, 0, 0);
                p1 = __builtin_amdgcn_mfma_f32_16x16x32_bf16(as[8 + ks], bp[8 + ks], p1, 0, 0, 0);
            }
            const int pcol = blkh * 16 + n;
            #pragma unroll
            for (int r = 0; r < 4; r++)
                outp[((size_t)(grow0 + kq * 4 + r) * kT + (t - 1)) * kD + pcol] = p0[r] + p1[r];
        }

        if (t + 1 < kT) {                              // prefetch x(t+1)
            #pragma unroll
            for (int ks = 0; ks < 8; ks++) {
                const float4* xp = (const float4*)(x + ((size_t)mrow * kT + (t + 1)) * kD + ks * 32 + kq * 8);
                float4 a0 = xp[0], a1 = xp[1];
                U4 f;
                f.u[0] = pk2(a0.x, a0.y); f.u[1] = pk2(a0.z, a0.w);
                f.u[2] = pk2(a1.x, a1.y); f.u[3] = pk2(a1.z, a1.w);
                ax[ks] = f.v;
            }
        }
    }
}

extern "C" void kernel_launch(void* const* d_in, const int* in_sizes, int n_in,
                              void* d_out, int out_size, void* d_ws, size_t ws_size,
                              hipStream_t stream) {
    const float* x1   = (const float*)d_in[0];
    const float* x2   = (const float*)d_in[1];
    const float* wih1 = (const float*)d_in[2];
    const float* whh1 = (const float*)d_in[3];
    const float* b1   = (const float*)d_in[4];
    const float* whr1 = (const float*)d_in[5];
    const float* wih2 = (const float*)d_in[6];
    const float* whh2 = (const float*)d_in[7];
    const float* b2   = (const float*)d_in[8];
    const float* whr2 = (const float*)d_in[9];
    float* outp  = (float*)d_out;
    unsigned* ws = (unsigned*)d_ws;

    bar_init_kernel<<<65, 1024, 0, stream>>>(ws);
    lstm2_kernel<<<dim3(kNB), dim3(kNT), 0, stream>>>(
        x1, x2, wih1, whh1, b1, whr1, wih2, whh2, b2, whr2, outp, ws);
}

// Round 7
// 2957.202 us; speedup vs baseline: 2.0544x; 1.0370x over previous
//
#include <hip/hip_runtime.h>

// R7: XCD-local s-exchange. R4-R6 invariant 7.3us/step = per-step chain of
// cross-XCD fabric RTs (agent-scope sc0sc1 ops, ~700cyc each: publish-ack,
// tag-prop, detect, stage) + barrier jitter. Remap teams to bid%8 (= XCD
// round-robin) so each 32-block team is XCD-resident; exchange via L2:
// plain stores + sc0 (L1-bypass) loads, ~150-200cyc/hop. Placement VERIFIED
// via HW_REG_XCC_ID; non-homogeneous teams fall back to agent-scope (R6).
// Cross-replay L2 staleness: one-time agent fence (wbl2+inv) before
// barrier1 + in-kernel zeroing of tags/SD by the owning team.
// Teams are batch-partitioned => fully independent => per-team mode safe.
constexpr int kB = 64, kT = 512, kD = 256, kH = 512, kG = 2048;
constexpr int kNB = 256, kNT = 256;

typedef __attribute__((ext_vector_type(8))) short bf16x8;
typedef __attribute__((ext_vector_type(4))) float f32x4;
typedef unsigned long long ull;
union U4 { unsigned u[4]; ull q[2]; bf16x8 v; };

__device__ __forceinline__ ushort f2bf(float x) {
    union { float f; unsigned u; } v; v.f = x;
    unsigned r = v.u + 0x7FFFu + ((v.u >> 16) & 1u);
    return (ushort)(r >> 16);
}
__device__ __forceinline__ unsigned pk2(float a, float b) {
    return (unsigned)f2bf(a) | ((unsigned)f2bf(b) << 16);
}
__device__ __forceinline__ float sigm(float x) { return 1.f / (1.f + __expf(-x)); }

#define AT_LOAD(p)     __hip_atomic_load((p), __ATOMIC_RELAXED, __HIP_MEMORY_SCOPE_AGENT)
#define AT_LOAD64(p)   __hip_atomic_load((p), __ATOMIC_RELAXED, __HIP_MEMORY_SCOPE_AGENT)
#define AT_STORE(p,v)  __hip_atomic_store((p), (v), __ATOMIC_RELAXED, __HIP_MEMORY_SCOPE_AGENT)
#define AT_ADD(p,v)    __hip_atomic_fetch_add((p), (v), __ATOMIC_RELAXED, __HIP_MEMORY_SCOPE_AGENT)
#define VMCNT0() asm volatile("s_waitcnt vmcnt(0)" ::: "memory")

// L2-scope (intra-XCD) vs agent-scope transport helpers; 'fast' is uniform.
__device__ __forceinline__ unsigned ld_dw(const unsigned* p, bool fast) {
    unsigned r;
    if (fast) asm volatile("global_load_dword %0, %1, off sc0\n\ts_waitcnt vmcnt(0)"
                           : "=v"(r) : "v"(p) : "memory");
    else r = AT_LOAD(p);
    return r;
}
__device__ __forceinline__ void ld8q(const ull* p, ull* q, bool fast) {
    if (fast) {
        asm volatile(
            "global_load_dwordx2 %0, %8, off sc0\n\t"
            "global_load_dwordx2 %1, %8, off offset:8 sc0\n\t"
            "global_load_dwordx2 %2, %8, off offset:16 sc0\n\t"
            "global_load_dwordx2 %3, %8, off offset:24 sc0\n\t"
            "global_load_dwordx2 %4, %8, off offset:32 sc0\n\t"
            "global_load_dwordx2 %5, %8, off offset:40 sc0\n\t"
            "global_load_dwordx2 %6, %8, off offset:48 sc0\n\t"
            "global_load_dwordx2 %7, %8, off offset:56 sc0\n\t"
            "s_waitcnt vmcnt(0)"
            : "=v"(q[0]), "=v"(q[1]), "=v"(q[2]), "=v"(q[3]),
              "=v"(q[4]), "=v"(q[5]), "=v"(q[6]), "=v"(q[7])
            : "v"(p) : "memory");
    } else {
        #pragma unroll
        for (int i = 0; i < 8; i++) q[i] = AT_LOAD64(p + i);
    }
}
__device__ __forceinline__ void st_u16(ushort* p, ushort v, bool fast) {
    if (fast) *p = v;
    else __hip_atomic_store(p, v, __ATOMIC_RELAXED, __HIP_MEMORY_SCOPE_AGENT);
}
__device__ __forceinline__ void st_dw(unsigned* p, unsigned v, bool fast) {
    if (fast) *p = v;
    else AT_STORE(p, v);
}

// ws dword layout:
//  [0] ctr1  [64] flag1  [128] ctr2  [192] flag2
//  [256..768)   TG tags: (team*2+par)*32 + rank
//  [768..1024)  XC[bid] xcc ids
//  [1024..66560) SD slabs: (team*2+par)*4096 dw, row-major [16][512] bf16
//  [66560..)    WC: Wc bf16 [l][2048][512]
__global__ void bar_init_kernel(unsigned* ws) {
    AT_STORE(ws + threadIdx.x, 0u);   // 1024 threads cover flags+tags+XC
}

__global__ void __launch_bounds__(kNT, 1) lstm2_kernel(
    const float* __restrict__ x1, const float* __restrict__ x2,
    const float* __restrict__ wih1, const float* __restrict__ whh1,
    const float* __restrict__ b1,   const float* __restrict__ whr1,
    const float* __restrict__ wih2, const float* __restrict__ whh2,
    const float* __restrict__ b2,   const float* __restrict__ whr2,
    float* __restrict__ out, unsigned* __restrict__ ws)
{
    const int bid = blockIdx.x, tid = threadIdx.x;
    const int team = bid & 7, rank = bid >> 3;         // team = XCD (if round-robin)
    const int l = team >> 2, bteam = team & 3, blkh = rank;
    const int h0 = blkh * 16, grow0 = bteam * 16;

    const float* x   = l ? x2 : x1;
    const float* wih = l ? wih2 : wih1;
    const float* whh = l ? whh2 : whh1;
    const float* bb  = l ? b2 : b1;
    const float* whr = l ? whr2 : whr1;
    float* outp = out + (l ? (size_t)0 : (size_t)kB * kT * kD);

    unsigned* TG  = ws + 256;
    unsigned* XC  = ws + 768;
    unsigned* SDB = ws + 1024;
    unsigned* WC  = ws + 66560;

    __shared__ unsigned sst[16 * 268];
    __shared__ float lgs[4][16][17];

    // one-time cache clean: flush+inv stale L2 lines from previous replays
    __builtin_amdgcn_fence(__ATOMIC_SEQ_CST, "agent");
    VMCNT0();

    unsigned xcc;
    asm volatile("s_getreg_b32 %0, hwreg(HW_REG_XCC_ID)" : "=s"(xcc));
    xcc &= 15u;
    if (tid == 0) AT_STORE(XC + bid, xcc);

    // ---------- P0: Wc = Whh @ Whr (f32 accum -> bf16, agent-scope) ----------
    {
        const int wlin = bteam * 32 + rank;            // 0..127 within LSTM
        const int j  = wlin * 16 + (tid >> 4);         // gate row 0..2047
        const int k0 = (tid & 15) * 32;
        const float* whh_r = whh + (size_t)j * kD;
        float acc[32];
        #pragma unroll
        for (int i = 0; i < 32; i++) acc[i] = 0.f;
        for (int p = 0; p < kD; p++) {
            float w = whh_r[p];
            const float4* wr = (const float4*)(whr + (size_t)p * kH + k0);
            #pragma unroll
            for (int q = 0; q < 8; q++) {
                float4 v = wr[q];
                acc[q*4+0] = fmaf(w, v.x, acc[q*4+0]);
                acc[q*4+1] = fmaf(w, v.y, acc[q*4+1]);
                acc[q*4+2] = fmaf(w, v.z, acc[q*4+2]);
                acc[q*4+3] = fmaf(w, v.w, acc[q*4+3]);
            }
        }
        unsigned* dst = WC + (size_t)l * kG * 256 + (size_t)j * 256 + k0 / 2;
        #pragma unroll
        for (int i = 0; i < 16; i++) AT_STORE(dst + i, pk2(acc[2*i], acc[2*i+1]));
    }
    // barrier 1: all fences + Wc + XC stores complete
    VMCNT0();
    __syncthreads();
    if (tid == 0) {
        unsigned a = AT_ADD(ws + 0, 1u);
        if (a == (unsigned)(kNB - 1)) AT_STORE(ws + 64, 1u);
        while (AT_LOAD(ws + 64) == 0u) __builtin_amdgcn_s_sleep(2);
    }
    __syncthreads();

    // ---------- placement check: is this team XCD-homogeneous? --------------
    const int lane = tid & 63;
    unsigned x0 = AT_LOAD(XC + team);
    unsigned xr = (lane < 32) ? AT_LOAD(XC + team + 8 * lane) : x0;
    const bool fast = __all((int)(xr == x0));

    // ---------- zero own team's tags + SD slabs (in current owner's L2) -----
    if (rank == 0 && tid < 64) st_dw(TG + team * 64 + tid, 0u, fast);
    if (tid < 128) {
        st_dw(SDB + (size_t)(team * 2 + 0) * 4096 + rank * 128 + tid, 0u, fast);
        st_dw(SDB + (size_t)(team * 2 + 1) * 4096 + rank * 128 + tid, 0u, fast);
    }

    // ---------- persistent fragments -----------------------------------------
    const int wv = tid >> 6;
    const int n = lane & 15, kq = lane >> 4;
    const int gcol = wv * kH + h0 + n;
    const float bias = bb[gcol];
    const int mrow = grow0 + n;
    const int crow = tid >> 4, ccol = tid & 15;

    bf16x8 bxh[8];                                     // Wih frags (K=256)
    #pragma unroll
    for (int ks = 0; ks < 8; ks++) {
        const float4* p = (const float4*)(wih + (size_t)gcol * kD + ks * 32 + kq * 8);
        float4 a0 = p[0], a1 = p[1];
        U4 h;
        h.u[0] = pk2(a0.x, a0.y); h.u[1] = pk2(a0.z, a0.w);
        h.u[2] = pk2(a1.x, a1.y); h.u[3] = pk2(a1.z, a1.w);
        bxh[ks] = h.v;
    }
    bf16x8 bsh[16];                                    // Wc frags (K=512)
    {
        const ull* wcp = (const ull*)(WC + (size_t)l * kG * 256 + (size_t)gcol * 256);
        #pragma unroll
        for (int ks = 0; ks < 16; ks++) {
            U4 u;
            u.q[0] = AT_LOAD64(wcp + ks * 8 + kq * 2 + 0);
            u.q[1] = AT_LOAD64(wcp + ks * 8 + kq * 2 + 1);
            bsh[ks] = u.v;
        }
    }
    const bool isProj = (blkh < 16);
    bf16x8 bp[16];                                     // Whr frags (proj blocks)
    if (isProj) {
        const int pcol = blkh * 16 + n;
        #pragma unroll
        for (int ks = 0; ks < 16; ks++) {
            const float4* p = (const float4*)(whr + (size_t)pcol * kH + ks * 32 + kq * 8);
            float4 a0 = p[0], a1 = p[1];
            U4 h;
            h.u[0] = pk2(a0.x, a0.y); h.u[1] = pk2(a0.z, a0.w);
            h.u[2] = pk2(a1.x, a1.y); h.u[3] = pk2(a1.z, a1.w);
            bp[ks] = h.v;
        }
    }
    bf16x8 ax[8];                                      // x(0) frags
    #pragma unroll
    for (int ks = 0; ks < 8; ks++) {
        const float4* xp = (const float4*)(x + (size_t)mrow * kT * kD + ks * 32 + kq * 8);
        float4 a0 = xp[0], a1 = xp[1];
        U4 f;
        f.u[0] = pk2(a0.x, a0.y); f.u[1] = pk2(a0.z, a0.w);
        f.u[2] = pk2(a1.x, a1.y); f.u[3] = pk2(a1.z, a1.w);
        ax[ks] = f.v;
    }
    float creg = 0.f;
    const int srow = tid >> 4, scol = (tid & 15) * 16;

    // barrier 2: zeroing + all prologue loads complete everywhere
    VMCNT0();
    __syncthreads();
    if (tid == 0) {
        unsigned a = AT_ADD(ws + 128, 1u);
        if (a == (unsigned)(kNB - 1)) AT_STORE(ws + 192, 1u);
        while (AT_LOAD(ws + 192) == 0u) __builtin_amdgcn_s_sleep(2);
    }
    __syncthreads();

    // ---------- main loop: poll -> stage -> MFMA -> cell -> publish ----------
    for (int t = 0; t <= kT; ++t) {
        if (t == kT && !isProj) break;
        const int par = (t + 1) & 1;
        const unsigned want = (unsigned)t;
        const unsigned* tagp = TG + (team * 2 + par) * 32;
        while (true) {
            unsigned tg = want;
            if (lane < 32) tg = ld_dw(tagp + lane, fast);
            if (__all((int)(tg >= want))) break;
            __builtin_amdgcn_s_sleep(1);
        }
        __builtin_amdgcn_sched_barrier(0);

        {   // stage s(t-1) slab: 64B per thread, L2-local when fast
            const ull* sp = (const ull*)(SDB + (size_t)(team * 2 + par) * 4096
                                             + srow * 256 + scol);
            ull q[8];
            ld8q(sp, q, fast);
            ull* ld = (ull*)&sst[srow * 268 + scol];
            #pragma unroll
            for (int i = 0; i < 8; i++) ld[i] = q[i];
        }
        __syncthreads();
        bf16x8 as[16];
        #pragma unroll
        for (int ks = 0; ks < 16; ks++)
            as[ks] = *(const bf16x8*)&sst[n * 268 + ks * 16 + kq * 4];

        if (t < kT) {
            f32x4 c0 = {bias, bias, bias, bias};
            f32x4 c1 = {0.f, 0.f, 0.f, 0.f};
            f32x4 c2 = {0.f, 0.f, 0.f, 0.f};
            #pragma unroll
            for (int ks = 0; ks < 8; ks++) {
                c0 = __builtin_amdgcn_mfma_f32_16x16x32_bf16(ax[ks],   bxh[ks],   c0, 0, 0, 0);
                c1 = __builtin_amdgcn_mfma_f32_16x16x32_bf16(as[ks],   bsh[ks],   c1, 0, 0, 0);
                c2 = __builtin_amdgcn_mfma_f32_16x16x32_bf16(as[8+ks], bsh[8+ks], c2, 0, 0, 0);
            }
            #pragma unroll
            for (int r = 0; r < 4; r++)
                lgs[wv][kq * 4 + r][n] = c0[r] + c1[r] + c2[r];
            __syncthreads();
            const float gi = sigm(lgs[0][crow][ccol]);
            const float gf = sigm(lgs[1][crow][ccol]);
            const float gg = tanhf(lgs[2][crow][ccol]);
            const float go = sigm(lgs[3][crow][ccol]);
            creg = gf * creg + gi * gg;
            const float sv = go * tanhf(creg);
            ushort* sd = (ushort*)(SDB + (size_t)(team * 2 + (t & 1)) * 4096);
            st_u16(sd + crow * 512 + h0 + ccol, f2bf(sv), fast);
            VMCNT0();
            __syncthreads();
            if (tid == 0)
                st_dw(TG + (team * 2 + (t & 1)) * 32 + rank, (unsigned)(t + 1), fast);
        }

        if (t >= 1 && isProj) {                        // out(t-1), sync shadow
            f32x4 p0 = {0.f, 0.f, 0.f, 0.f};
            f32x4 p1 = {0.f, 0.f, 0.f, 0.f};
            #pragma unroll
            for (int ks = 0; ks < 8; ks++) {
                p0 = __builtin_amdgcn_mfma_f32_16x16x32_bf16(as[ks],     bp[ks],     p0, 0, 0, 0);
                p1 = __builtin_amdgcn_mfma_f32_16x16x32_bf16(as[8 + ks], bp[8 + ks], p1, 0, 0, 0);
            }
            const int pcol = blkh * 16 + n;
            #pragma unroll
            for (int r = 0; r < 4; r++)
                outp[((size_t)(grow0 + kq * 4 + r) * kT + (t - 1)) * kD + pcol] = p0[r] + p1[r];
        }

        if (t + 1 < kT) {                              // prefetch x(t+1)
            #pragma unroll
            for (int ks = 0; ks < 8; ks++) {
                const float4* xp = (const float4*)(x + ((size_t)mrow * kT + (t + 1)) * kD + ks * 32 + kq * 8);
                float4 a0 = xp[0], a1 = xp[1];
                U4 f;
                f.u[0] = pk2(a0.x, a0.y); f.u[1] = pk2(a0.z, a0.w);
                f.u[2] = pk2(a1.x, a1.y); f.u[3] = pk2(a1.z, a1.w);
                ax[ks] = f.v;
            }
        }
    }
}

extern "C" void kernel_launch(void* const* d_in, const int* in_sizes, int n_in,
                              void* d_out, int out_size, void* d_ws, size_t ws_size,
                              hipStream_t stream) {
    const float* x1   = (const float*)d_in[0];
    const float* x2   = (const float*)d_in[1];
    const float* wih1 = (const float*)d_in[2];
    const float* whh1 = (const float*)d_in[3];
    const float* b1   = (const float*)d_in[4];
    const float* whr1 = (const float*)d_in[5];
    const float* wih2 = (const float*)d_in[6];
    const float* whh2 = (const float*)d_in[7];
    const float* b2   = (const float*)d_in[8];
    const float* whr2 = (const float*)d_in[9];
    float* outp  = (float*)d_out;
    unsigned* ws = (unsigned*)d_ws;

    bar_init_kernel<<<1, 1024, 0, stream>>>(ws);
    lstm2_kernel<<<dim3(kNB), dim3(kNT), 0, stream>>>(
        x1, x2, wih1, whh1, b1, whr1, wih2, whh2, b2, whr2, outp, ws);
}

// Round 10
// 2937.758 us; speedup vs baseline: 2.0680x; 1.0066x over previous
//
#include <hip/hip_runtime.h>

// R10 = R7 (known-good, 2.96ms) with ONE delta: sleepless main-loop poll.
// R8/R9's direct-frag+hoist rewrite fails deterministically (bit-identical
// absmax across two compiles => structural bug, not a race) - abandoned.
// R4/R6/R7 period invariant ~7.3us across 3 different transports while
// chain arithmetic says ~1.2us => suspect DPM downclock (kernel 97% idle,
// s_sleep hints idleness; 2.4GHz->~500MHz floor explains the exact ratio).
// Removing s_sleep keeps waves active (clock up) + kills detect lag.
constexpr int kB = 64, kT = 512, kD = 256, kH = 512, kG = 2048;
constexpr int kNB = 256, kNT = 256;

typedef __attribute__((ext_vector_type(8))) short bf16x8;
typedef __attribute__((ext_vector_type(4))) float f32x4;
typedef unsigned long long ull;
union U4 { unsigned u[4]; ull q[2]; bf16x8 v; };

__device__ __forceinline__ ushort f2bf(float x) {
    union { float f; unsigned u; } v; v.f = x;
    unsigned r = v.u + 0x7FFFu + ((v.u >> 16) & 1u);
    return (ushort)(r >> 16);
}
__device__ __forceinline__ unsigned pk2(float a, float b) {
    return (unsigned)f2bf(a) | ((unsigned)f2bf(b) << 16);
}
__device__ __forceinline__ float sigm(float x) { return 1.f / (1.f + __expf(-x)); }

#define AT_LOAD(p)     __hip_atomic_load((p), __ATOMIC_RELAXED, __HIP_MEMORY_SCOPE_AGENT)
#define AT_LOAD64(p)   __hip_atomic_load((p), __ATOMIC_RELAXED, __HIP_MEMORY_SCOPE_AGENT)
#define AT_STORE(p,v)  __hip_atomic_store((p), (v), __ATOMIC_RELAXED, __HIP_MEMORY_SCOPE_AGENT)
#define AT_ADD(p,v)    __hip_atomic_fetch_add((p), (v), __ATOMIC_RELAXED, __HIP_MEMORY_SCOPE_AGENT)
#define VMCNT0() asm volatile("s_waitcnt vmcnt(0)" ::: "memory")

__device__ __forceinline__ unsigned ld_dw(const unsigned* p, bool fast) {
    unsigned r;
    if (fast) asm volatile("global_load_dword %0, %1, off sc0\n\ts_waitcnt vmcnt(0)"
                           : "=&v"(r) : "v"(p) : "memory");
    else r = AT_LOAD(p);
    return r;
}
__device__ __forceinline__ void ld8q(const ull* p, ull* q, bool fast) {
    if (fast) {
        asm volatile(
            "global_load_dwordx2 %0, %8, off sc0\n\t"
            "global_load_dwordx2 %1, %8, off offset:8 sc0\n\t"
            "global_load_dwordx2 %2, %8, off offset:16 sc0\n\t"
            "global_load_dwordx2 %3, %8, off offset:24 sc0\n\t"
            "global_load_dwordx2 %4, %8, off offset:32 sc0\n\t"
            "global_load_dwordx2 %5, %8, off offset:40 sc0\n\t"
            "global_load_dwordx2 %6, %8, off offset:48 sc0\n\t"
            "global_load_dwordx2 %7, %8, off offset:56 sc0\n\t"
            "s_waitcnt vmcnt(0)"
            : "=&v"(q[0]), "=&v"(q[1]), "=&v"(q[2]), "=&v"(q[3]),
              "=&v"(q[4]), "=&v"(q[5]), "=&v"(q[6]), "=&v"(q[7])
            : "v"(p) : "memory");
    } else {
        #pragma unroll
        for (int i = 0; i < 8; i++) q[i] = AT_LOAD64(p + i);
    }
}
__device__ __forceinline__ void st_u16(ushort* p, ushort v, bool fast) {
    if (fast) *p = v;
    else __hip_atomic_store(p, v, __ATOMIC_RELAXED, __HIP_MEMORY_SCOPE_AGENT);
}
__device__ __forceinline__ void st_dw(unsigned* p, unsigned v, bool fast) {
    if (fast) *p = v;
    else AT_STORE(p, v);
}

// ws dword layout:
//  [0] ctr1  [64] flag1  [128] ctr2  [192] flag2
//  [256..768)   TG tags: (team*2+par)*32 + rank
//  [768..1024)  XC[bid] xcc ids
//  [1024..66560) SD slabs: (team*2+par)*4096 dw, row-major [16][512] bf16
//  [66560..)    WC: Wc bf16 [l][2048][512]
__global__ void bar_init_kernel(unsigned* ws) {
    AT_STORE(ws + threadIdx.x, 0u);
}

__global__ void __launch_bounds__(kNT, 1) lstm2_kernel(
    const float* __restrict__ x1, const float* __restrict__ x2,
    const float* __restrict__ wih1, const float* __restrict__ whh1,
    const float* __restrict__ b1,   const float* __restrict__ whr1,
    const float* __restrict__ wih2, const float* __restrict__ whh2,
    const float* __restrict__ b2,   const float* __restrict__ whr2,
    float* __restrict__ out, unsigned* __restrict__ ws)
{
    const int bid = blockIdx.x, tid = threadIdx.x;
    const int team = bid & 7, rank = bid >> 3;         // team = XCD (if round-robin)
    const int l = team >> 2, bteam = team & 3, blkh = rank;
    const int h0 = blkh * 16, grow0 = bteam * 16;

    const float* x   = l ? x2 : x1;
    const float* wih = l ? wih2 : wih1;
    const float* whh = l ? whh2 : whh1;
    const float* bb  = l ? b2 : b1;
    const float* whr = l ? whr2 : whr1;
    float* outp = out + (l ? (size_t)0 : (size_t)kB * kT * kD);

    unsigned* TG  = ws + 256;
    unsigned* XC  = ws + 768;
    unsigned* SDB = ws + 1024;
    unsigned* WC  = ws + 66560;

    __shared__ unsigned sst[16 * 268];
    __shared__ float lgs[4][16][17];

    // one-time cache clean: flush+inv stale L2 lines from previous replays
    __builtin_amdgcn_fence(__ATOMIC_SEQ_CST, "agent");
    VMCNT0();

    unsigned xcc;
    asm volatile("s_getreg_b32 %0, hwreg(HW_REG_XCC_ID)" : "=s"(xcc));
    xcc &= 15u;
    if (tid == 0) AT_STORE(XC + bid, xcc);

    // ---------- P0: Wc = Whh @ Whr (f32 accum -> bf16, agent-scope) ----------
    {
        const int wlin = bteam * 32 + rank;            // 0..127 within LSTM
        const int j  = wlin * 16 + (tid >> 4);         // gate row 0..2047
        const int k0 = (tid & 15) * 32;
        const float* whh_r = whh + (size_t)j * kD;
        float acc[32];
        #pragma unroll
        for (int i = 0; i < 32; i++) acc[i] = 0.f;
        for (int p = 0; p < kD; p++) {
            float w = whh_r[p];
            const float4* wr = (const float4*)(whr + (size_t)p * kH + k0);
            #pragma unroll
            for (int q = 0; q < 8; q++) {
                float4 v = wr[q];
                acc[q*4+0] = fmaf(w, v.x, acc[q*4+0]);
                acc[q*4+1] = fmaf(w, v.y, acc[q*4+1]);
                acc[q*4+2] = fmaf(w, v.z, acc[q*4+2]);
                acc[q*4+3] = fmaf(w, v.w, acc[q*4+3]);
            }
        }
        unsigned* dst = WC + (size_t)l * kG * 256 + (size_t)j * 256 + k0 / 2;
        #pragma unroll
        for (int i = 0; i < 16; i++) AT_STORE(dst + i, pk2(acc[2*i], acc[2*i+1]));
    }
    // barrier 1: all fences + Wc + XC stores complete
    VMCNT0();
    __syncthreads();
    if (tid == 0) {
        unsigned a = AT_ADD(ws + 0, 1u);
        if (a == (unsigned)(kNB - 1)) AT_STORE(ws + 64, 1u);
        while (AT_LOAD(ws + 64) == 0u) __builtin_amdgcn_s_sleep(2);
    }
    __syncthreads();

    // ---------- placement check: is this team XCD-homogeneous? --------------
    const int lane = tid & 63;
    unsigned x0 = AT_LOAD(XC + team);
    unsigned xr = (lane < 32) ? AT_LOAD(XC + team + 8 * lane) : x0;
    const bool fast = __all((int)(xr == x0));

    // ---------- zero own team's tags + SD slabs (in current owner's L2) -----
    if (rank == 0 && tid < 64) st_dw(TG + team * 64 + tid, 0u, fast);
    if (tid < 128) {
        st_dw(SDB + (size_t)(team * 2 + 0) * 4096 + rank * 128 + tid, 0u, fast);
        st_dw(SDB + (size_t)(team * 2 + 1) * 4096 + rank * 128 + tid, 0u, fast);
    }

    // ---------- persistent fragments -----------------------------------------
    const int wv = tid >> 6;
    const int n = lane & 15, kq = lane >> 4;
    const int gcol = wv * kH + h0 + n;
    const float bias = bb[gcol];
    const int mrow = grow0 + n;
    const int crow = tid >> 4, ccol = tid & 15;

    bf16x8 bxh[8];                                     // Wih frags (K=256)
    #pragma unroll
    for (int ks = 0; ks < 8; ks++) {
        const float4* p = (const float4*)(wih + (size_t)gcol * kD + ks * 32 + kq * 8);
        float4 a0 = p[0], a1 = p[1];
        U4 h;
        h.u[0] = pk2(a0.x, a0.y); h.u[1] = pk2(a0.z, a0.w);
        h.u[2] = pk2(a1.x, a1.y); h.u[3] = pk2(a1.z, a1.w);
        bxh[ks] = h.v;
    }
    bf16x8 bsh[16];                                    // Wc frags (K=512)
    {
        const ull* wcp = (const ull*)(WC + (size_t)l * kG * 256 + (size_t)gcol * 256);
        #pragma unroll
        for (int ks = 0; ks < 16; ks++) {
            U4 u;
            u.q[0] = AT_LOAD64(wcp + ks * 8 + kq * 2 + 0);
            u.q[1] = AT_LOAD64(wcp + ks * 8 + kq * 2 + 1);
            bsh[ks] = u.v;
        }
    }
    const bool isProj = (blkh < 16);
    bf16x8 bp[16];                                     // Whr frags (proj blocks)
    if (isProj) {
        const int pcol = blkh * 16 + n;
        #pragma unroll
        for (int ks = 0; ks < 16; ks++) {
            const float4* p = (const float4*)(whr + (size_t)pcol * kH + ks * 32 + kq * 8);
            float4 a0 = p[0], a1 = p[1];
            U4 h;
            h.u[0] = pk2(a0.x, a0.y); h.u[1] = pk2(a0.z, a0.w);
            h.u[2] = pk2(a1.x, a1.y); h.u[3] = pk2(a1.z, a1.w);
            bp[ks] = h.v;
        }
    }
    bf16x8 ax[8];                                      // x(0) frags
    #pragma unroll
    for (int ks = 0; ks < 8; ks++) {
        const float4* xp = (const float4*)(x + (size_t)mrow * kT * kD + ks * 32 + kq * 8);
        float4 a0 = xp[0], a1 = xp[1];
        U4 f;
        f.u[0] = pk2(a0.x, a0.y); f.u[1] = pk2(a0.z, a0.w);
        f.u[2] = pk2(a1.x, a1.y); f.u[3] = pk2(a1.z, a1.w);
        ax[ks] = f.v;
    }
    float creg = 0.f;
    const int srow = tid >> 4, scol = (tid & 15) * 16;

    // barrier 2: zeroing + all prologue loads complete everywhere
    VMCNT0();
    __syncthreads();
    if (tid == 0) {
        unsigned a = AT_ADD(ws + 128, 1u);
        if (a == (unsigned)(kNB - 1)) AT_STORE(ws + 192, 1u);
        while (AT_LOAD(ws + 192) == 0u) __builtin_amdgcn_s_sleep(2);
    }
    __syncthreads();

    // ---------- main loop: poll -> stage -> MFMA -> cell -> publish ----------
    for (int t = 0; t <= kT; ++t) {
        if (t == kT && !isProj) break;
        const int par = (t + 1) & 1;
        const unsigned want = (unsigned)t;
        const unsigned* tagp = TG + (team * 2 + par) * 32;
        while (true) {                                 // HARD spin: no s_sleep
            unsigned tg = want;
            if (lane < 32) tg = ld_dw(tagp + lane, fast);
            if (__all((int)(tg >= want))) break;
        }
        __builtin_amdgcn_sched_barrier(0);

        {   // stage s(t-1) slab: 64B per thread, L2-local when fast
            const ull* sp = (const ull*)(SDB + (size_t)(team * 2 + par) * 4096
                                             + srow * 256 + scol);
            ull q[8];
            ld8q(sp, q, fast);
            ull* ld = (ull*)&sst[srow * 268 + scol];
            #pragma unroll
            for (int i = 0; i < 8; i++) ld[i] = q[i];
        }
        __syncthreads();
        bf16x8 as[16];
        #pragma unroll
        for (int ks = 0; ks < 16; ks++)
            as[ks] = *(const bf16x8*)&sst[n * 268 + ks * 16 + kq * 4];

        if (t < kT) {
            f32x4 c0 = {bias, bias, bias, bias};
            f32x4 c1 = {0.f, 0.f, 0.f, 0.f};
            f32x4 c2 = {0.f, 0.f, 0.f, 0.f};
            #pragma unroll
            for (int ks = 0; ks < 8; ks++) {
                c0 = __builtin_amdgcn_mfma_f32_16x16x32_bf16(ax[ks],   bxh[ks],   c0, 0, 0, 0);
                c1 = __builtin_amdgcn_mfma_f32_16x16x32_bf16(as[ks],   bsh[ks],   c1, 0, 0, 0);
                c2 = __builtin_amdgcn_mfma_f32_16x16x32_bf16(as[8+ks], bsh[8+ks], c2, 0, 0, 0);
            }
            #pragma unroll
            for (int r = 0; r < 4; r++)
                lgs[wv][kq * 4 + r][n] = c0[r] + c1[r] + c2[r];
            __syncthreads();
            const float gi = sigm(lgs[0][crow][ccol]);
            const float gf = sigm(lgs[1][crow][ccol]);
            const float gg = tanhf(lgs[2][crow][ccol]);
            const float go = sigm(lgs[3][crow][ccol]);
            creg = gf * creg + gi * gg;
            const float sv = go * tanhf(creg);
            ushort* sd = (ushort*)(SDB + (size_t)(team * 2 + (t & 1)) * 4096);
            st_u16(sd + crow * 512 + h0 + ccol, f2bf(sv), fast);
            VMCNT0();
            __syncthreads();
            if (tid == 0)
                st_dw(TG + (team * 2 + (t & 1)) * 32 + rank, (unsigned)(t + 1), fast);
        }

        if (t >= 1 && isProj) {                        // out(t-1), sync shadow
            f32x4 p0 = {0.f, 0.f, 0.f, 0.f};
            f32x4 p1 = {0.f, 0.f, 0.f, 0.f};
            #pragma unroll
            for (int ks = 0; ks < 8; ks++) {
                p0 = __builtin_amdgcn_mfma_f32_16x16x32_bf16(as[ks],     bp[ks],     p0, 0, 0, 0);
                p1 = __builtin_amdgcn_mfma_f32_16x16x32_bf16(as[8 + ks], bp[8 + ks], p1, 0, 0, 0);
            }
            const int pcol = blkh * 16 + n;
            #pragma unroll
            for (int r = 0; r < 4; r++)
                outp[((size_t)(grow0 + kq * 4 + r) * kT + (t - 1)) * kD + pcol] = p0[r] + p1[r];
        }

        if (t + 1 < kT) {                              // prefetch x(t+1)
            #pragma unroll
            for (int ks = 0; ks < 8; ks++) {
                const float4* xp = (const float4*)(x + ((size_t)mrow * kT + (t + 1)) * kD + ks * 32 + kq * 8);
                float4 a0 = xp[0], a1 = xp[1];
                U4 f;
                f.u[0] = pk2(a0.x, a0.y); f.u[1] = pk2(a0.z, a0.w);
                f.u[2] = pk2(a1.x, a1.y); f.u[3] = pk2(a1.z, a1.w);
                ax[ks] = f.v;
            }
        }
    }
}

extern "C" void kernel_launch(void* const* d_in, const int* in_sizes, int n_in,
                              void* d_out, int out_size, void* d_ws, size_t ws_size,
                              hipStream_t stream) {
    const float* x1   = (const float*)d_in[0];
    const float* x2   = (const float*)d_in[1];
    const float* wih1 = (const float*)d_in[2];
    const float* whh1 = (const float*)d_in[3];
    const float* b1   = (const float*)d_in[4];
    const float* whr1 = (const float*)d_in[5];
    const float* wih2 = (const float*)d_in[6];
    const float* whh2 = (const float*)d_in[7];
    const float* b2   = (const float*)d_in[8];
    const float* whr2 = (const float*)d_in[9];
    float* outp  = (float*)d_out;
    unsigned* ws = (unsigned*)d_ws;

    bar_init_kernel<<<1, 1024, 0, stream>>>(ws);
    lstm2_kernel<<<dim3(kNB), dim3(kNT), 0, stream>>>(
        x1, x2, wih1, whh1, b1, whr1, wih2, whh2, b2, whr2, outp, ws);
}